// Round 4
// baseline (358.183 us; speedup 1.0000x reference)
//
#include <hip/hip_runtime.h>
#include <hip/hip_bf16.h>

#define N_NODES 65536
#define N_EDGES 524288
#define BS 512

typedef __attribute__((ext_vector_type(8))) short bf16x8;
typedef __attribute__((ext_vector_type(4))) float f32x4;

// ---------------- degree / count ----------------
__global__ void deg_init_k(float* __restrict__ deg) {
    int i = blockIdx.x * 256 + threadIdx.x;
    deg[i] = 1.0f;  // self-loop weight
}
__global__ void deg_cnt_k(const int* __restrict__ dst, const float* __restrict__ w,
                          float* __restrict__ deg, int* __restrict__ cnt) {
    int e = blockIdx.x * 256 + threadIdx.x;
    int d = dst[e];
    atomicAdd(&deg[d], w[e]);
    atomicAdd(&cnt[d], 1);
}
__global__ void deg_fin_k(float* __restrict__ deg) {
    int i = blockIdx.x * 256 + threadIdx.x;
    deg[i] = rsqrtf(deg[i]);
}

// ---------------- exclusive prefix sum of 65536 ints (single block) ------------
__global__ __launch_bounds__(1024) void scan_k(const int* __restrict__ cnt,
                                               int* __restrict__ rp) {
    __shared__ int sums[1024];
    int t = threadIdx.x;
    int base = t * 64;
    int s = 0;
#pragma unroll
    for (int i = 0; i < 64; ++i) s += cnt[base + i];
    sums[t] = s;
    __syncthreads();
    for (int d = 1; d < 1024; d <<= 1) {
        int v = (t >= d) ? sums[t - d] : 0;
        __syncthreads();
        if (t >= d) sums[t] += v;
        __syncthreads();
    }
    int run = (t == 0) ? 0 : sums[t - 1];
#pragma unroll
    for (int i = 0; i < 64; ++i) {
        rp[base + i] = run;
        run += cnt[base + i];
    }
    if (t == 1023) rp[65536] = run;
}

// ---------------- scatter edges into dst-sorted CSR order ---------------------
__global__ void scatter_k(const int* __restrict__ src, const int* __restrict__ dst,
                          const float* __restrict__ w, const float* __restrict__ dinv,
                          int* __restrict__ cursor, int* __restrict__ ssrc,
                          float* __restrict__ scoef) {
    int e = blockIdx.x * 256 + threadIdx.x;
    int s = src[e], d = dst[e];
    int pos = atomicAdd(&cursor[d], 1);
    ssrc[pos] = s;
    scoef[pos] = dinv[s] * w[e] * dinv[d];
}

// ---------------- gather SpMM: ybf[n] = bf16( P x )[n] ------------------------
__global__ __launch_bounds__(256) void gather_k(const int* __restrict__ rp,
                                                const int* __restrict__ ssrc,
                                                const float* __restrict__ scoef,
                                                const float* __restrict__ x,
                                                const float* __restrict__ dinv,
                                                __hip_bfloat16* __restrict__ ybf) {
    int n = (blockIdx.x * 256 + threadIdx.x) >> 6;
    int lane = threadIdx.x & 63;
    int beg = rp[n], end = rp[n + 1];
    float di = dinv[n];
    float2 acc;
    {
        float2 xv = *(const float2*)(x + (size_t)n * 128 + lane * 2);
        float c = di * di;
        acc.x = c * xv.x;
        acc.y = c * xv.y;
    }
    int s0 = 0;
    float c0 = 0.f;
    if (beg < end) { s0 = ssrc[beg]; c0 = scoef[beg]; }
    for (int i = beg; i < end; ++i) {
        int s1 = 0;
        float c1 = 0.f;
        if (i + 1 < end) { s1 = ssrc[i + 1]; c1 = scoef[i + 1]; }
        float2 xv = *(const float2*)(x + (size_t)s0 * 128 + lane * 2);
        acc.x += c0 * xv.x;
        acc.y += c0 * xv.y;
        s0 = s1;
        c0 = c1;
    }
    alignas(4) __hip_bfloat16 o[2] = {__float2bfloat16(acc.x), __float2bfloat16(acc.y)};
    *(unsigned int*)((unsigned short*)ybf + (size_t)n * 128 + lane * 2) =
        *(const unsigned int*)o;
}

// ---------------- W_comb^T = (w1_gcn2 @ w_gcn)^T in bf16, layout [f][c] -------
__global__ void wcomb_k(const float* __restrict__ w1, const float* __restrict__ wg,
                        __hip_bfloat16* __restrict__ WT) {
    int t = blockIdx.x * 256 + threadIdx.x;  // 512*128
    int f = t >> 7, c = t & 127;
    float s = 0.f;
#pragma unroll 8
    for (int m = 0; m < 128; ++m) s += w1[c * 128 + m] * wg[m * 512 + f];
    WT[t] = __float2bfloat16(s);
}

// ---------------- fp32 -> bf16 vectorized conversion --------------------------
__global__ void f2b_k(const float* __restrict__ in, __hip_bfloat16* __restrict__ out) {
    int i = (blockIdx.x * 256 + threadIdx.x) * 4;
    float4 v = *(const float4*)(in + i);
    alignas(8) __hip_bfloat16 tmp[4] = {__float2bfloat16(v.x), __float2bfloat16(v.y),
                                        __float2bfloat16(v.z), __float2bfloat16(v.w)};
    *(ushort4*)((unsigned short*)out + i) = *(const ushort4*)tmp;
}

// ---------------- async global -> LDS, 16B per lane ---------------------------
__device__ __forceinline__ void gll16(const void* g, void* l) {
    __builtin_amdgcn_global_load_lds(
        (const __attribute__((address_space(1))) void*)g,
        (__attribute__((address_space(3))) void*)l, 16, 0, 0);
}

// ============================================================================
// Mega-fused per-graph kernel: one block = one graph (128 nodes = 32 V-rows).
//   y(128x128 bf16, LDS) -> for g in 0..3: h2g = tanh(y_g @ WT + bg) (32x512,
//   LDS) ; acc2 += h2g @ wc1[:, g*512:+512]^T  -> act1 = relu(acc2+bc1) (LDS)
//   -> act2 = relu(act1 @ wc2^T + bc2) (regs) -> dot with wlin -> sigmoid.
// LDS: [0,32KB) y tile (128 rows x 256B, swizzled) later reused as act1 tile
//      (32 rows x 1024B, swizzled); [32KB,64KB) h2g tile (32 x 1024B, swizzled).
// Swizzle: byte ^= ((row&7)<<4)  (fixes 16-way bank conflict on row-stride
// 256B/1024B ds_read_b128 column reads).
// ============================================================================
__global__ __launch_bounds__(512, 2) void fused_k(
    const __hip_bfloat16* __restrict__ ybf,
    const __hip_bfloat16* __restrict__ WTbf,   // [512][128]
    const float* __restrict__ bg,              // [512]
    const __hip_bfloat16* __restrict__ wc1bf,  // [512][2048]
    const float* __restrict__ bc1,             // [512]
    const __hip_bfloat16* __restrict__ wc2bf,  // [256][512]
    const float* __restrict__ bc2,             // [256]
    const float* __restrict__ wlin,            // [8192]
    const float* __restrict__ blin,            // [1]
    float* __restrict__ out) {
    __shared__ char lds[65536];
    const int tid = threadIdx.x;
    const int lane = tid & 63, wid = tid >> 6;
    const int b = blockIdx.x;
    const int l15 = lane & 15, lhi = lane >> 4;

    // ---- stage y tile (32KB) with pre-swizzled global source ----
    {
        const char* ysrc = (const char*)(ybf + (size_t)b * 128 * 128);
#pragma unroll
        for (int r = 0; r < 4; ++r) {
            int abase = r * 8192 + wid * 1024;      // wave-uniform LDS dest
            int a = abase + lane * 16;              // this lane's dest byte
            int src = a ^ (((a >> 8) & 7) << 4);    // inverse-swizzled source
            gll16(ysrc + src, lds + abase);
        }
    }

    // bias prefetch (per-lane columns are fixed across g)
    float bgv[4], bc1v[4], bc2v[2];
#pragma unroll
    for (int j = 0; j < 4; ++j) bgv[j] = bg[wid * 64 + j * 16 + l15];
#pragma unroll
    for (int j = 0; j < 4; ++j) bc1v[j] = bc1[wid * 64 + j * 16 + l15];
#pragma unroll
    for (int j = 0; j < 2; ++j) bc2v[j] = bc2[wid * 32 + j * 16 + l15];

    f32x4 acc2[2][4] = {};
    __syncthreads();  // y staged (vmcnt drained before barrier)

    for (int g = 0; g < 4; ++g) {
        // ---- GEMM1: h2g[m,f] = tanh(y[g*32+m,:] @ WT[f,:] + bg[f]) ----
        f32x4 acc1[2][4] = {};
#pragma unroll
        for (int kt = 0; kt < 4; ++kt) {
            bf16x8 af[2], bfv[4];
#pragma unroll
            for (int mi = 0; mi < 2; ++mi) {
                int row = g * 32 + mi * 16 + l15;
                int logical = row * 256 + kt * 64 + lhi * 16;
                af[mi] = *(const bf16x8*)(lds + (logical ^ ((row & 7) << 4)));
            }
#pragma unroll
            for (int nj = 0; nj < 4; ++nj) {
                int n = wid * 64 + nj * 16 + l15;
                bfv[nj] = *(const bf16x8*)(WTbf + n * 128 + kt * 32 + lhi * 8);
            }
#pragma unroll
            for (int mi = 0; mi < 2; ++mi)
#pragma unroll
                for (int nj = 0; nj < 4; ++nj)
                    acc1[mi][nj] = __builtin_amdgcn_mfma_f32_16x16x32_bf16(
                        af[mi], bfv[nj], acc1[mi][nj], 0, 0, 0);
        }
        // wait for ALL waves to finish previous GEMM2's H-region reads
        __syncthreads();
#pragma unroll
        for (int mi = 0; mi < 2; ++mi)
#pragma unroll
            for (int nj = 0; nj < 4; ++nj)
#pragma unroll
                for (int r = 0; r < 4; ++r) {
                    int m = mi * 16 + lhi * 4 + r;
                    int f = wid * 64 + nj * 16 + l15;
                    float v = acc1[mi][nj][r] + bgv[nj];
                    v = 1.0f - 2.0f / (__expf(2.0f * v) + 1.0f);  // tanh
                    int logical = m * 1024 + f * 2;
                    *(__hip_bfloat16*)(lds + 32768 + (logical ^ ((m & 7) << 4))) =
                        __float2bfloat16(v);
                }
        __syncthreads();

        // ---- GEMM2: acc2 += h2g @ wc1[:, g*512:+512]^T (K=512) ----
#pragma unroll 2
        for (int kt = 0; kt < 16; ++kt) {
            bf16x8 af[2], bfv[4];
#pragma unroll
            for (int mi = 0; mi < 2; ++mi) {
                int row = mi * 16 + l15;
                int logical = row * 1024 + kt * 64 + lhi * 16;
                af[mi] = *(const bf16x8*)(lds + 32768 + (logical ^ ((row & 7) << 4)));
            }
#pragma unroll
            for (int nj = 0; nj < 4; ++nj) {
                int n = wid * 64 + nj * 16 + l15;
                bfv[nj] = *(const bf16x8*)(wc1bf + (size_t)n * 2048 + g * 512 +
                                           kt * 32 + lhi * 8);
            }
#pragma unroll
            for (int mi = 0; mi < 2; ++mi)
#pragma unroll
                for (int nj = 0; nj < 4; ++nj)
                    acc2[mi][nj] = __builtin_amdgcn_mfma_f32_16x16x32_bf16(
                        af[mi], bfv[nj], acc2[mi][nj], 0, 0, 0);
        }
    }

    // ---- act1 = relu(acc2 + bc1) -> bf16 -> Y region (32 x 1024B, swizzled) ----
    // (Y region reads all completed before the barrier preceding GEMM2 g=3)
#pragma unroll
    for (int mi = 0; mi < 2; ++mi)
#pragma unroll
        for (int nj = 0; nj < 4; ++nj)
#pragma unroll
            for (int r = 0; r < 4; ++r) {
                int m = mi * 16 + lhi * 4 + r;
                int o = wid * 64 + nj * 16 + l15;
                float v = fmaxf(acc2[mi][nj][r] + bc1v[nj], 0.0f);
                int logical = m * 1024 + o * 2;
                *(__hip_bfloat16*)(lds + (logical ^ ((m & 7) << 4))) =
                    __float2bfloat16(v);
            }
    __syncthreads();

    // ---- GEMM3: act2 = relu(act1 @ wc2^T + bc2): M=32, N=256, K=512 ----
    f32x4 acc3[2][2] = {};
#pragma unroll 2
    for (int kt = 0; kt < 16; ++kt) {
        bf16x8 af[2], bfv[2];
#pragma unroll
        for (int mi = 0; mi < 2; ++mi) {
            int row = mi * 16 + l15;
            int logical = row * 1024 + kt * 64 + lhi * 16;
            af[mi] = *(const bf16x8*)(lds + (logical ^ ((row & 7) << 4)));
        }
#pragma unroll
        for (int nj = 0; nj < 2; ++nj) {
            int n = wid * 32 + nj * 16 + l15;
            bfv[nj] = *(const bf16x8*)(wc2bf + n * 512 + kt * 32 + lhi * 8);
        }
#pragma unroll
        for (int mi = 0; mi < 2; ++mi)
#pragma unroll
            for (int nj = 0; nj < 2; ++nj)
                acc3[mi][nj] = __builtin_amdgcn_mfma_f32_16x16x32_bf16(
                    af[mi], bfv[nj], acc3[mi][nj], 0, 0, 0);
    }

    // ---- final dot: out[b] = sigmoid(sum_{e,p} act2[e,p]*wlin[p*32+e] + blin) ----
    float part = 0.f;
#pragma unroll
    for (int mi = 0; mi < 2; ++mi)
#pragma unroll
        for (int nj = 0; nj < 2; ++nj)
#pragma unroll
            for (int r = 0; r < 4; ++r) {
                int e = mi * 16 + lhi * 4 + r;
                int p = wid * 32 + nj * 16 + l15;
                float v = fmaxf(acc3[mi][nj][r] + bc2v[nj], 0.0f);
                part += v * wlin[p * 32 + e];
            }
#pragma unroll
    for (int off = 32; off > 0; off >>= 1) part += __shfl_down(part, off, 64);
    __syncthreads();
    float* red = (float*)(lds + 32768);
    if (lane == 0) red[wid] = part;
    __syncthreads();
    if (tid == 0) {
        float tot = blin[0];
#pragma unroll
        for (int i = 0; i < 8; ++i) tot += red[i];
        out[b] = 1.0f / (1.0f + __expf(-tot));
    }
}

extern "C" void kernel_launch(void* const* d_in, const int* in_sizes, int n_in,
                              void* d_out, int out_size, void* d_ws, size_t ws_size,
                              hipStream_t stream) {
    const float* x    = (const float*)d_in[0];
    const float* eattr= (const float*)d_in[1];
    const float* w1   = (const float*)d_in[2];
    const float* wg   = (const float*)d_in[3];
    const float* bg   = (const float*)d_in[4];
    const float* wc1  = (const float*)d_in[5];
    const float* bc1  = (const float*)d_in[6];
    const float* wc2  = (const float*)d_in[7];
    const float* bc2  = (const float*)d_in[8];
    const float* wlin = (const float*)d_in[9];
    const float* blin = (const float*)d_in[10];
    const int*   ei   = (const int*)d_in[11];
    const int* esrc = ei;
    const int* edst = ei + N_EDGES;
    float* out = (float*)d_out;

    // workspace layout (bytes, 16B aligned)
    char* ws = (char*)d_ws;
    float*          dinv   = (float*)(ws + 0);          // 262144
    int*            cnt    = (int*)(ws + 262144);       // 262144
    int*            rp     = (int*)(ws + 524288);       // 262160 (65537 ints)
    int*            cursor = (int*)(ws + 786688);       // 262144
    int*            ssrc   = (int*)(ws + 1048832);      // 2097152
    float*          scoef  = (float*)(ws + 3145984);    // 2097152
    __hip_bfloat16* WTbf   = (__hip_bfloat16*)(ws + 5243136);   // 131072
    __hip_bfloat16* ybf    = (__hip_bfloat16*)(ws + 5374208);   // 16777216
    __hip_bfloat16* wc1bf  = (__hip_bfloat16*)(ws + 22151424);  // 2097152
    __hip_bfloat16* wc2bf  = (__hip_bfloat16*)(ws + 24248576);  // 262144
    if (ws_size < (size_t)24510720) return;

    // 1) degree + per-node edge counts
    hipMemsetAsync(cnt, 0, 262144, stream);
    deg_init_k<<<N_NODES / 256, 256, 0, stream>>>(dinv);
    deg_cnt_k<<<N_EDGES / 256, 256, 0, stream>>>(edst, eattr, dinv, cnt);
    deg_fin_k<<<N_NODES / 256, 256, 0, stream>>>(dinv);

    // 2) CSR build: row_ptr + dst-sorted (src, coef)
    scan_k<<<1, 1024, 0, stream>>>(cnt, rp);
    hipMemcpyAsync(cursor, rp, 262144, hipMemcpyDeviceToDevice, stream);
    scatter_k<<<N_EDGES / 256, 256, 0, stream>>>(esrc, edst, eattr, dinv,
                                                 cursor, ssrc, scoef);

    // 3) gather SpMM -> ybf (bf16)
    gather_k<<<N_NODES / 4, 256, 0, stream>>>(rp, ssrc, scoef, x, dinv, ybf);

    // 4) weights: W_comb^T (bf16) + bf16 conversions
    wcomb_k<<<(512 * 128) / 256, 256, 0, stream>>>(w1, wg, WTbf);
    f2b_k<<<(512 * 2048 / 4) / 256, 256, 0, stream>>>(wc1, wc1bf);
    f2b_k<<<(256 * 512 / 4) / 256, 256, 0, stream>>>(wc2, wc2bf);

    // 5) fused per-graph pipeline: h2 -> cnn1 -> cnn2 -> linear -> sigmoid
    fused_k<<<BS, 512, 0, stream>>>(ybf, WTbf, bg, wc1bf, bc1, wc2bf, bc2,
                                    wlin, blin, out);
}

// Round 5
// 327.648 us; speedup vs baseline: 1.0932x; 1.0932x over previous
//
#include <hip/hip_runtime.h>
#include <hip/hip_bf16.h>

#define N_NODES 65536
#define N_EDGES 524288
#define BS 512

typedef __attribute__((ext_vector_type(8))) short bf16x8;
typedef __attribute__((ext_vector_type(4))) float f32x4;

__device__ __forceinline__ float bf2f(unsigned short u) {
    union { unsigned int i; float f; } v;
    v.i = ((unsigned int)u) << 16;
    return v.f;
}

// ---------------- degree / count ----------------
__global__ void deg_init_k(float* __restrict__ deg) {
    int i = blockIdx.x * 256 + threadIdx.x;
    deg[i] = 1.0f;  // self-loop weight
}
__global__ void deg_cnt_k(const int* __restrict__ dst, const float* __restrict__ w,
                          float* __restrict__ deg, int* __restrict__ cnt) {
    int e = blockIdx.x * 256 + threadIdx.x;
    int d = dst[e];
    atomicAdd(&deg[d], w[e]);
    atomicAdd(&cnt[d], 1);
}
__global__ void deg_fin_k(float* __restrict__ deg) {
    int i = blockIdx.x * 256 + threadIdx.x;
    deg[i] = rsqrtf(deg[i]);
}

// ---------------- exclusive prefix sum of 65536 ints (single block) ------------
__global__ __launch_bounds__(1024) void scan_k(const int* __restrict__ cnt,
                                               int* __restrict__ rp) {
    __shared__ int sums[1024];
    int t = threadIdx.x;
    int base = t * 64;
    int s = 0;
#pragma unroll
    for (int i = 0; i < 64; ++i) s += cnt[base + i];
    sums[t] = s;
    __syncthreads();
    for (int d = 1; d < 1024; d <<= 1) {
        int v = (t >= d) ? sums[t - d] : 0;
        __syncthreads();
        if (t >= d) sums[t] += v;
        __syncthreads();
    }
    int run = (t == 0) ? 0 : sums[t - 1];
#pragma unroll
    for (int i = 0; i < 64; ++i) {
        rp[base + i] = run;
        run += cnt[base + i];
    }
    if (t == 1023) rp[65536] = run;
}

// ---------------- scatter edges into dst-sorted CSR order ---------------------
__global__ void scatter_k(const int* __restrict__ src, const int* __restrict__ dst,
                          const float* __restrict__ w, const float* __restrict__ dinv,
                          int* __restrict__ cursor, int* __restrict__ ssrc,
                          float* __restrict__ scoef) {
    int e = blockIdx.x * 256 + threadIdx.x;
    int s = src[e], d = dst[e];
    int pos = atomicAdd(&cursor[d], 1);
    ssrc[pos] = s;
    scoef[pos] = dinv[s] * w[e] * dinv[d];
}

// ---------------- x fp32 -> bf16 (halves gather traffic) ----------------------
__global__ void f2b_k(const float* __restrict__ in, __hip_bfloat16* __restrict__ out) {
    int i = (blockIdx.x * 256 + threadIdx.x) * 4;
    float4 v = *(const float4*)(in + i);
    alignas(8) __hip_bfloat16 tmp[4] = {__float2bfloat16(v.x), __float2bfloat16(v.y),
                                        __float2bfloat16(v.z), __float2bfloat16(v.w)};
    *(ushort4*)((unsigned short*)out + i) = *(const ushort4*)tmp;
}

// ---------------- gather SpMM on bf16 x: ybf[n] = bf16( P x )[n] ---------------
// one wave per node; lane holds channels [2l, 2l+1] (one dword of bf16x2)
__global__ __launch_bounds__(256) void gather_k(const int* __restrict__ rp,
                                                const int* __restrict__ ssrc,
                                                const float* __restrict__ scoef,
                                                const unsigned short* __restrict__ xbf,
                                                const float* __restrict__ dinv,
                                                __hip_bfloat16* __restrict__ ybf) {
    int n = (blockIdx.x * 256 + threadIdx.x) >> 6;
    int lane = threadIdx.x & 63;
    int beg = rp[n], end = rp[n + 1];
    float di = dinv[n];
    float accx, accy;
    {
        unsigned int u = *(const unsigned int*)(xbf + (size_t)n * 128 + lane * 2);
        float c = di * di;
        accx = c * bf2f((unsigned short)(u & 0xffff));
        accy = c * bf2f((unsigned short)(u >> 16));
    }
    int s0 = 0;
    float c0 = 0.f;
    if (beg < end) { s0 = ssrc[beg]; c0 = scoef[beg]; }
    for (int i = beg; i < end; ++i) {
        int s1 = 0;
        float c1 = 0.f;
        if (i + 1 < end) { s1 = ssrc[i + 1]; c1 = scoef[i + 1]; }
        unsigned int u = *(const unsigned int*)(xbf + (size_t)s0 * 128 + lane * 2);
        accx += c0 * bf2f((unsigned short)(u & 0xffff));
        accy += c0 * bf2f((unsigned short)(u >> 16));
        s0 = s1;
        c0 = c1;
    }
    alignas(4) __hip_bfloat16 o[2] = {__float2bfloat16(accx), __float2bfloat16(accy)};
    *(unsigned int*)((unsigned short*)ybf + (size_t)n * 128 + lane * 2) =
        *(const unsigned int*)o;
}

// ---------------- W_comb^T = (w1_gcn2 @ w_gcn)^T in bf16, layout [f][c] -------
__global__ void wcomb_k(const float* __restrict__ w1, const float* __restrict__ wg,
                        __hip_bfloat16* __restrict__ WT) {
    int t = blockIdx.x * 256 + threadIdx.x;  // 512*128
    int f = t >> 7, c = t & 127;
    float s = 0.f;
#pragma unroll 8
    for (int m = 0; m < 128; ++m) s += w1[c * 128 + m] * wg[m * 512 + f];
    WT[t] = __float2bfloat16(s);
}

// ---------------- async global -> LDS, 16B per lane ---------------------------
__device__ __forceinline__ void gll16(const void* g, void* l) {
    __builtin_amdgcn_global_load_lds(
        (const __attribute__((address_space(1))) void*)g,
        (__attribute__((address_space(3))) void*)l, 16, 0, 0);
}

// ---------------- bf16 MFMA GEMM: C = act(A @ B^T + bias) ---------------------
// A: M x K bf16 row-major. B: N x K bf16 row-major ((out,in) weights).
// ACT: 0 none, 1 relu, 2 tanh.
// OUT_MODE: 0 fp32 row-major, 1 bf16 row-major, 2 bf16 with rearrange-permute.
// 128x128 tile, BK=32, 4 waves (2x2), each wave 64x64 via 4x4 16x16x32 frags.
template <int ACT, int OUT_MODE>
__global__ __launch_bounds__(256) void gemm_mfma_k(
    const __hip_bfloat16* __restrict__ A, const __hip_bfloat16* __restrict__ B,
    const float* __restrict__ bias, void* __restrict__ Cout,
    int M, int N, int K) {
    __shared__ char lds[16384];  // A tile 8KB | B tile 8KB
    char* ldsA = lds;
    char* ldsB = lds + 8192;

    const int tid = threadIdx.x;
    const int lane = tid & 63, wid = tid >> 6;
    const int bm = blockIdx.y * 128, bn = blockIdx.x * 128;
    const int wr = wid >> 1, wc = wid & 1;

    const int srow = wid * 16 + (lane >> 2);
    const int skcol = (lane & 3) * 8;
    const __hip_bfloat16* Abase = A + (size_t)(bm + srow) * K + skcol;
    const __hip_bfloat16* Bbase = B + (size_t)(bn + srow) * K + skcol;
    const int ldso = wid * 1024;

    f32x4 acc[4][4] = {};

    const int lrow = lane & 15;
    const int lkb = (lane >> 4) * 16;

    for (int kt = 0; kt < K; kt += 32) {
        gll16(Abase + kt,                  ldsA + ldso);
        gll16(Abase + kt + (size_t)64 * K, ldsA + 4096 + ldso);
        gll16(Bbase + kt,                  ldsB + ldso);
        gll16(Bbase + kt + (size_t)64 * K, ldsB + 4096 + ldso);
        __syncthreads();

        bf16x8 af[4], bfr[4];
#pragma unroll
        for (int i = 0; i < 4; ++i)
            af[i] = *(const bf16x8*)(ldsA + (wr * 64 + i * 16 + lrow) * 64 + lkb);
#pragma unroll
        for (int j = 0; j < 4; ++j)
            bfr[j] = *(const bf16x8*)(ldsB + (wc * 64 + j * 16 + lrow) * 64 + lkb);
#pragma unroll
        for (int i = 0; i < 4; ++i)
#pragma unroll
            for (int j = 0; j < 4; ++j)
                acc[i][j] = __builtin_amdgcn_mfma_f32_16x16x32_bf16(
                    af[i], bfr[j], acc[i][j], 0, 0, 0);
        __syncthreads();
    }

    const int crow0 = wr * 64 + (lane >> 4) * 4;
    const int ccol0 = wc * 64 + (lane & 15);
#pragma unroll
    for (int i = 0; i < 4; ++i) {
#pragma unroll
        for (int j = 0; j < 4; ++j) {
            int col = bn + ccol0 + j * 16;
            float bv = bias[col];
#pragma unroll
            for (int r = 0; r < 4; ++r) {
                int row = bm + crow0 + i * 16 + r;
                float v = acc[i][j][r] + bv;
                if (ACT == 1) v = fmaxf(v, 0.f);
                if (ACT == 2) v = tanhf(v);
                if (OUT_MODE == 0) {
                    ((float*)Cout)[(size_t)row * N + col] = v;
                } else if (OUT_MODE == 1) {
                    ((__hip_bfloat16*)Cout)[(size_t)row * N + col] = __float2bfloat16(v);
                } else {
                    size_t prow = (size_t)(((row >> 7) << 5) | (row & 31));
                    size_t idx = prow * 2048 + (size_t)(((row >> 5) & 3) * 512 + col);
                    ((__hip_bfloat16*)Cout)[idx] = __float2bfloat16(v);
                }
            }
        }
    }
}

// ---------------- final: out[b] = sigmoid(sum act2[(b*32+e), p] * wlin[p*32+e]) ----
__global__ __launch_bounds__(256) void final_k(const float* __restrict__ act2,
                                               const float* __restrict__ wlin,
                                               const float* __restrict__ blin,
                                               float* __restrict__ out) {
    int b = blockIdx.x;
    int t = threadIdx.x;
    float s = 0.f;
#pragma unroll 8
    for (int e = 0; e < 32; ++e)
        s += act2[((size_t)(b * 32 + e)) * 256 + t] * wlin[t * 32 + e];
#pragma unroll
    for (int off = 32; off > 0; off >>= 1) s += __shfl_down(s, off, 64);
    __shared__ float partial[4];
    if ((t & 63) == 0) partial[t >> 6] = s;
    __syncthreads();
    if (t == 0) {
        float tot = partial[0] + partial[1] + partial[2] + partial[3] + blin[0];
        out[b] = 1.f / (1.f + expf(-tot));
    }
}

extern "C" void kernel_launch(void* const* d_in, const int* in_sizes, int n_in,
                              void* d_out, int out_size, void* d_ws, size_t ws_size,
                              hipStream_t stream) {
    const float* x    = (const float*)d_in[0];
    const float* eattr= (const float*)d_in[1];
    const float* w1   = (const float*)d_in[2];
    const float* wg   = (const float*)d_in[3];
    const float* bg   = (const float*)d_in[4];
    const float* wc1  = (const float*)d_in[5];
    const float* bc1  = (const float*)d_in[6];
    const float* wc2  = (const float*)d_in[7];
    const float* bc2  = (const float*)d_in[8];
    const float* wlin = (const float*)d_in[9];
    const float* blin = (const float*)d_in[10];
    const int*   ei   = (const int*)d_in[11];
    const int* esrc = ei;
    const int* edst = ei + N_EDGES;
    float* out = (float*)d_out;

    // workspace layout (bytes, 16B aligned)
    char* ws = (char*)d_ws;
    float*          dinv   = (float*)(ws + 0);          // 262144
    int*            cnt    = (int*)(ws + 262144);       // 262144
    int*            rp     = (int*)(ws + 524288);       // 262160 (65537 ints)
    int*            cursor = (int*)(ws + 786688);       // 262144
    int*            ssrc   = (int*)(ws + 1048832);      // 2097152
    float*          scoef  = (float*)(ws + 3145984);    // 2097152
    __hip_bfloat16* WTbf   = (__hip_bfloat16*)(ws + 5243136);   // 131072
    __hip_bfloat16* ybf    = (__hip_bfloat16*)(ws + 5374208);   // 16777216
    __hip_bfloat16* V      = (__hip_bfloat16*)(ws + 22151424);  // 67108864
    __hip_bfloat16* act1   = (__hip_bfloat16*)(ws + 89260288);  // 16777216
    float*          act2   = (float*)(ws + 106037504);  // 16777216
    __hip_bfloat16* wc1bf  = (__hip_bfloat16*)(ws + 122814720); // 2097152
    __hip_bfloat16* wc2bf  = (__hip_bfloat16*)(ws + 124911872); // 262144
    __hip_bfloat16* xbf    = (__hip_bfloat16*)(ws + 125174016); // 16777216
    if (ws_size < (size_t)141951232) return;

    // 1) degree + per-node edge counts ; x -> bf16 in parallel
    hipMemsetAsync(cnt, 0, 262144, stream);
    deg_init_k<<<N_NODES / 256, 256, 0, stream>>>(dinv);
    deg_cnt_k<<<N_EDGES / 256, 256, 0, stream>>>(edst, eattr, dinv, cnt);
    deg_fin_k<<<N_NODES / 256, 256, 0, stream>>>(dinv);
    f2b_k<<<(N_NODES * 128 / 4) / 256, 256, 0, stream>>>(x, xbf);

    // 2) CSR build: row_ptr + dst-sorted (src, coef)
    scan_k<<<1, 1024, 0, stream>>>(cnt, rp);
    hipMemcpyAsync(cursor, rp, 262144, hipMemcpyDeviceToDevice, stream);
    scatter_k<<<N_EDGES / 256, 256, 0, stream>>>(esrc, edst, eattr, dinv,
                                                 cursor, ssrc, scoef);

    // 3) gather SpMM on bf16 x -> ybf (bf16)
    gather_k<<<N_NODES / 4, 256, 0, stream>>>(rp, ssrc, scoef,
                                              (const unsigned short*)xbf, dinv, ybf);

    // 4) weights: W_comb^T (bf16) + bf16 conversions
    wcomb_k<<<(512 * 128) / 256, 256, 0, stream>>>(w1, wg, WTbf);
    f2b_k<<<(512 * 2048 / 4) / 256, 256, 0, stream>>>(wc1, wc1bf);
    f2b_k<<<(256 * 512 / 4) / 256, 256, 0, stream>>>(wc2, wc2bf);

    // 5) h2 = tanh(y @ W_comb + b_gcn) -> V (bf16, rearranged layout)
    gemm_mfma_k<2, 2><<<dim3(512 / 128, 65536 / 128), 256, 0, stream>>>(
        ybf, WTbf, bg, V, 65536, 512, 128);

    // 6) cnn1: act1 = relu(V @ wc1^T + bc1)  (16384 x 2048) x (512 x 2048)^T
    gemm_mfma_k<1, 1><<<dim3(512 / 128, 16384 / 128), 256, 0, stream>>>(
        V, wc1bf, bc1, act1, 16384, 512, 2048);

    // 7) cnn2: act2 = relu(act1 @ wc2^T + bc2)  (16384 x 512) x (256 x 512)^T
    gemm_mfma_k<1, 0><<<dim3(256 / 128, 16384 / 128), 256, 0, stream>>>(
        act1, wc2bf, bc2, act2, 16384, 256, 512);

    // 8) final linear + sigmoid
    final_k<<<BS, 256, 0, stream>>>(act2, wlin, blin, out);
}